// Round 8
// baseline (486.896 us; speedup 1.0000x reference)
//
#include <hip/hip_runtime.h>

// Cost volume: out[n,c,d,h,w] = left[n,c,h,w] * right[n,c,h,w-d] (w>=d else 0)
// N=2 C=32 H=136 W=240 D=48. Output 401 MB fp32.
//
// Round-10: DOUBLE-LAUNCH probe. Facts so far:
//  - R4 (4-row tile): dur 409.9, presumed kernel residue ~150us.
//  - R9 in-kernel double store pass: +41.7us marginal for a full extra 401MB
//    sweep -> store ISSUE+LDS+FMA is ~42us; ~108us of residue unexplained.
//  - All write-pattern theories refuted (R3 LDS, R4 NT/plain, R6 4x granule,
//    R7 fill-identical linear = WORSE).
// Survivors: B) ~60-90us of tiny-memset harness overhead inside dur_us
// (kernel actually ~75-100us, i.e. near the 64us write roofline);
// C') kernel drain genuinely ~3TB/s. Discriminator: launch the IDENTICAL
// kernel TWICE. Delta vs 409.9 = one full standalone kernel execution
// (warm-cache lower bound on kernel time = upper bound on harness overhead).
//  Delta 70-100 -> kernel near roofline, declare next round with arithmetic.
//  Delta 140-160 -> no fixed overhead; attack drain with MUBUF sc1/nt stores.
// Kernel body is byte-identical to R4.

constexpr int W    = 240;
constexpr int H    = 136;
constexpr int D    = 48;
constexpr int W4   = W / 4;          // 60 float4 per row
constexpr int ROWS = 4;              // h-rows per block
constexpr int NT   = H / ROWS;       // 34 h-tiles
constexpr int PAD  = D;              // 48 zero floats of left padding
constexpr int CLEN = PAD + W;        // 288 floats per shifted copy
constexpr int RTOT = 4 * ROWS * CLEN; // 4608 staged right floats

typedef float v4f __attribute__((ext_vector_type(4)));

__global__ __launch_bounds__(256) void cost_volume_kernel(
    const float* __restrict__ left,
    const float* __restrict__ right,
    float* __restrict__ out)
{
    __shared__ __align__(16) float sL[ROWS * W];
    __shared__ __align__(16) float sR[4][ROWS][CLEN];

    const int ht  = blockIdx.x;      // 0..NT-1
    const int nc  = blockIdx.y;      // 0..NC-1
    const int h0  = ht * ROWS;
    const int tid = threadIdx.x;

    const float* __restrict__ Lg = left  + (size_t)(nc * H + h0) * W;
    const float* __restrict__ Rg = right + (size_t)(nc * H + h0) * W;

    if (tid < ROWS * W4) {
        reinterpret_cast<v4f*>(sL)[tid] =
            reinterpret_cast<const v4f*>(Lg)[tid];
    }
    for (int y = tid; y < RTOT; y += 256) {
        const int j   = y / (ROWS * CLEN);
        const int rem = y - j * (ROWS * CLEN);
        const int r   = rem / CLEN;
        const int x   = rem - r * CLEN;
        const int src = x - PAD - j;
        sR[0][0][y] = (src >= 0) ? Rg[r * W + src] : 0.0f;
    }
    __syncthreads();

    if (tid >= ROWS * W4) return;    // 240 active threads

    const int r  = tid / W4;
    const int w4 = tid - r * W4;

    const v4f l4 = reinterpret_cast<const v4f*>(sL)[tid];

    v4f* __restrict__ o = reinterpret_cast<v4f*>(out)
        + ((size_t)nc * D * H + (h0 + r)) * (size_t)W4 + w4;
    const size_t ds4 = (size_t)H * W4;

    const v4f* C0 = reinterpret_cast<const v4f*>(sR[0][r]);
    const v4f* C1 = reinterpret_cast<const v4f*>(sR[1][r]);
    const v4f* C2 = reinterpret_cast<const v4f*>(sR[2][r]);
    const v4f* C3 = reinterpret_cast<const v4f*>(sR[3][r]);

    #pragma unroll
    for (int q = 0; q < D / 4; ++q) {
        const int base = w4 + PAD / 4 - q;     // aligned b128, conflict-free
        const v4f r0 = C0[base];
        const v4f r1 = C1[base];
        const v4f r2 = C2[base];
        const v4f r3 = C3[base];
        v4f* oq = o + (size_t)(4 * q) * ds4;
        oq[0]       = l4 * r0;
        oq[ds4]     = l4 * r1;
        oq[2 * ds4] = l4 * r2;
        oq[3 * ds4] = l4 * r3;
    }
}

extern "C" void kernel_launch(void* const* d_in, const int* in_sizes, int n_in,
                              void* d_out, int out_size, void* d_ws, size_t ws_size,
                              hipStream_t stream) {
    const float* left  = (const float*)d_in[0];
    const float* right = (const float*)d_in[1];
    float* out = (float*)d_out;
    const int rows = in_sizes[0] / W;   // N*C*H = 8704
    const int nc   = rows / H;          // N*C = 64
    dim3 grid(NT, nc);
    // DOUBLE-LAUNCH probe: identical kernel twice (idempotent writes).
    // dur_us - 409.9 = one standalone warm-cache kernel execution.
    cost_volume_kernel<<<grid, 256, 0, stream>>>(left, right, out);
    cost_volume_kernel<<<grid, 256, 0, stream>>>(left, right, out);
}